// Round 11
// baseline (732.389 us; speedup 1.0000x reference)
//
#include <hip/hip_runtime.h>
#include <math.h>

#define NN 2048
#define EE 1024
#define NBLK 1024

typedef unsigned long long ull;
typedef unsigned short ushortt;

// barrier state: zero-initialized at module load; protocol returns it to zero
// after every launch -> deterministic across graph replays.
__device__ int g_bar[8];

__device__ __forceinline__ void gridbar(int k) {
  __syncthreads();
  if (threadIdx.x == 0) {
    __threadfence();  // release: flush this block's phase writes (L2 wb)
    __hip_atomic_fetch_add(&g_bar[k], 1, __ATOMIC_ACQ_REL, __HIP_MEMORY_SCOPE_AGENT);
    while (__hip_atomic_load(&g_bar[k], __ATOMIC_ACQUIRE, __HIP_MEMORY_SCOPE_AGENT) < NBLK)
      __builtin_amdgcn_s_sleep(2);
    // passed-protocol: the last block through resets both slots; safe because
    // passed==NBLK implies every block has exited the spin above.
    int p = __hip_atomic_fetch_add(&g_bar[k + 4], 1, __ATOMIC_ACQ_REL, __HIP_MEMORY_SCOPE_AGENT);
    if (p == NBLK - 1) {
      __hip_atomic_store(&g_bar[k], 0, __ATOMIC_RELAXED, __HIP_MEMORY_SCOPE_AGENT);
      __hip_atomic_store(&g_bar[k + 4], 0, __ATOMIC_RELAXED, __HIP_MEMORY_SCOPE_AGENT);
    }
  }
  __syncthreads();
  __threadfence();  // acquire: invalidate stale L1/L2 before reading peers' data
}

// ---------------------------------------------------------------------------
// Single fused kernel, 1024 blocks x 256 threads, 4 blocks/CU co-resident.
// Phase 0: [0,256) rfill 8 rows/blk | [256,512) npb 8 rows/blk
//          [512,1024) cscan 2 cols/blk (2 waves/col, LDS merge)
// Phase 1: block per edge: ef gather + projection + col scores + w
// Phase 2: 2 nodes/blk: row scores + z gather + final linear -> out
// ---------------------------------------------------------------------------
__global__ __launch_bounds__(256, 4)
void k_fused(const float* __restrict__ H, const float* __restrict__ x,
             const float* __restrict__ W1, const float* __restrict__ b1,
             const float* __restrict__ W2, const float* __restrict__ b2,
             const float* __restrict__ Wlg, const float* __restrict__ bl,
             ushortt* __restrict__ elist, int* __restrict__ cnt, float* __restrict__ dn,
             ushortt* __restrict__ clist, int* __restrict__ ccnt, float* __restrict__ de,
             float* __restrict__ npb, float* __restrict__ epb, float* __restrict__ w,
             float* __restrict__ out) {
  __shared__ __align__(16) char smem_raw[35840];
  float* smf = (float*)smem_raw;
  int bid = blockIdx.x, t = threadIdx.x, wv = t >> 6, lane = t & 63;

  // ---------------- Phase 0 ----------------
  if (bid < 256) {
    // rfill: 8 rows/block; wave wv does rows bid*8+wv and bid*8+4+wv
    #pragma unroll
    for (int rr = 0; rr < 2; ++rr) {
      int n = bid * 8 + rr * 4 + wv;
      const float* row = H + (size_t)n * EE;
      int count = 0;
      #pragma unroll
      for (int i = 0; i < EE; i += 64) {
        float hv = row[i + lane];
        ull m = __ballot(hv != 0.f);
        int pos = count + __popcll(m & ((1ull << lane) - 1ull));
        if (hv != 0.f && pos < 128) elist[n * 128 + pos] = (ushortt)(i + lane);
        count += __popcll(m);
      }
      if (lane == 0) {
        cnt[n] = count;
        dn[n] = count ? rsqrtf((float)count) : 0.f;
      }
    }
  } else if (bid < 512) {
    // npb: 8 rows x 128 h; W1 node-half transposed in LDS
    float* Wt = smf;               // 64*129
    float* xl = smf + 64 * 129;    // 8*64
    int r0 = (bid - 256) * 8;
    #pragma unroll
    for (int p = 0; p < 32; ++p) {
      int j = t + p * 256;
      int h = j >> 6, d = j & 63;
      Wt[d * 129 + h] = W1[h * 128 + d];
    }
    {
      int r = t >> 6, d = t & 63;
      xl[(r + 0) * 64 + d] = x[(size_t)(r0 + r) * 64 + d];
      xl[(r + 4) * 64 + d] = x[(size_t)(r0 + r + 4) * 64 + d];
    }
    __syncthreads();
    #pragma unroll
    for (int k = 0; k < 4; ++k) {
      int idx = t + k * 256;
      int row = idx >> 7, h = idx & 127;
      float acc = b1[h];
      #pragma unroll 8
      for (int d = 0; d < 64; ++d)
        acc += xl[row * 64 + d] * Wt[d * 129 + h];
      npb[(size_t)(r0 + row) * 128 + h] = acc;
    }
  } else {
    // cscan: 2 cols/block; waves (0,1)->e0 halves, (2,3)->e0+1 halves
    ushortt* cbuf = (ushortt*)smem_raw;               // [4][160]
    int* csh = (int*)(smem_raw + 4 * 160 * 2);        // [4]
    int e = (bid - 512) * 2 + (wv >> 1);
    int half = wv & 1;
    int count = 0;
    int r0 = half * 1024;
    #pragma unroll
    for (int i = 0; i < 16; ++i) {
      int r = r0 + i * 64 + lane;
      float hv = H[(size_t)r * EE + e];
      ull m = __ballot(hv != 0.f);
      int pos = count + __popcll(m & ((1ull << lane) - 1ull));
      if (hv != 0.f && pos < 160) cbuf[wv * 160 + pos] = (ushortt)r;
      count += __popcll(m);
    }
    if (lane == 0) csh[wv] = count;
    __syncthreads();
    int c0 = min(csh[wv & 2], 160);      // first-half (capped) count for this edge
    int myc = min(count, 160);
    int base = half ? c0 : 0;
    for (int i = lane; i < myc; i += 64) {
      int p = base + i;
      if (p < 192) clist[e * 192 + p] = cbuf[wv * 160 + i];
    }
    if (half == 0 && lane == 0) {
      int tot = csh[wv] + csh[wv + 1];
      ccnt[e] = tot;
      de[e] = tot ? 1.f / (float)tot : 0.f;
    }
  }

  gridbar(0);

  // ---------------- Phase 1: block per edge ----------------
  {
    float* Wt = smf;                       // 64*129  (33024 B)
    float* psum = smf + 64 * 129;          // [4][64]
    float* efl = psum + 256;               // [64]
    float* epl = efl + 64;                 // [128]
    float* pp = epl + 128;                 // [2][128]
    int e = bid;
    #pragma unroll
    for (int p = 0; p < 32; ++p) {
      int j = t + p * 256;
      int h = j >> 6, d = j & 63;
      Wt[d * 129 + h] = W1[h * 128 + 64 + d];
    }
    int c = min(ccnt[e], 192);
    // ef gather (wave-strided entries, coalesced x rows)
    float acc = 0.f;
    for (int j = wv; j < c; j += 4) {
      int n = clist[e * 192 + j];
      acc += x[(size_t)n * 64 + lane];
    }
    psum[wv * 64 + lane] = acc;
    __syncthreads();
    if (wv == 0)
      efl[lane] = psum[0 * 64 + lane] + psum[1 * 64 + lane] +
                  psum[2 * 64 + lane] + psum[3 * 64 + lane];
    __syncthreads();
    // projection: 256 threads = 128 h x 2 d-halves
    {
      int h = t & 127, hf = t >> 7;
      float a = 0.f;
      #pragma unroll 8
      for (int d = hf * 32; d < hf * 32 + 32; ++d)
        a += efl[d] * Wt[d * 129 + h];
      pp[hf * 128 + h] = a;
    }
    __syncthreads();
    if (t < 128) {
      float v = pp[t] + pp[128 + t];
      epl[t] = v;
      epb[(size_t)e * 128 + t] = v;
    }
    __syncthreads();
    // col scores + weighted gather
    float epa = epl[lane], epc = epl[64 + lane];
    float w2a = W2[lane], w2b = W2[64 + lane];
    float b2v = b2[0];
    float accw = 0.f;
    for (int j = wv; j < c; j += 4) {
      int n = clist[e * 192 + j];
      float sc = fmaxf(npb[(size_t)n * 128 + lane] + epa, 0.f) * w2a
               + fmaxf(npb[(size_t)n * 128 + 64 + lane] + epc, 0.f) * w2b;
      #pragma unroll
      for (int o = 32; o > 0; o >>= 1) sc += __shfl_xor(sc, o, 64);
      float s = dn[n] / (1.f + __expf(-(sc + b2v)));
      accw += s * x[(size_t)n * 64 + lane];
    }
    __syncthreads();
    psum[wv * 64 + lane] = accw;
    __syncthreads();
    if (wv == 0)
      w[(size_t)e * 64 + lane] =
          de[e] * (psum[0 * 64 + lane] + psum[1 * 64 + lane] +
                   psum[2 * 64 + lane] + psum[3 * 64 + lane]);
  }

  gridbar(1);

  // ---------------- Phase 2: 2 nodes per block ----------------
  {
    float* Wlds = smf;                     // 64*65 (16640 B)
    float* psum = smf + 64 * 65;           // [4][64]
    float* zl = psum + 256;                // [2][64]
    float* pp = zl + 128;                  // [2][128]
    int n0 = bid * 2;
    #pragma unroll
    for (int p = 0; p < 16; ++p) {
      int j = t + p * 256;
      Wlds[(j >> 6) * 65 + (j & 63)] = Wlg[j];
    }
    __syncthreads();
    int nodesub = wv >> 1;
    int n = n0 + nodesub;
    int c = min(cnt[n], 128);
    float npa = npb[(size_t)n * 128 + lane], npc = npb[(size_t)n * 128 + 64 + lane];
    float w2a = W2[lane], w2b = W2[64 + lane];
    float b2v = b2[0];
    float acc = 0.f;
    for (int j = wv & 1; j < c; j += 2) {
      int e = elist[n * 128 + j];
      float sc = fmaxf(npa + epb[(size_t)e * 128 + lane], 0.f) * w2a
               + fmaxf(npc + epb[(size_t)e * 128 + 64 + lane], 0.f) * w2b;
      #pragma unroll
      for (int o = 32; o > 0; o >>= 1) sc += __shfl_xor(sc, o, 64);
      float s = 1.f / (1.f + __expf(-(sc + b2v)));
      acc += s * w[(size_t)e * 64 + lane];
    }
    psum[wv * 64 + lane] = acc;
    __syncthreads();
    if ((wv & 1) == 0)
      zl[nodesub * 64 + lane] =
          dn[n] * (psum[wv * 64 + lane] + psum[(wv + 1) * 64 + lane]);
    __syncthreads();
    // final linear: 256 threads = 2 nodes x 64 o x 2 d-halves
    {
      int o = t & 63, nd = (t >> 6) & 1, dh = t >> 7;
      float po = 0.f;
      #pragma unroll
      for (int d = dh * 32; d < dh * 32 + 32; ++d)
        po += zl[nd * 64 + d] * Wlds[o * 65 + d];
      pp[dh * 128 + nd * 64 + o] = po;
    }
    __syncthreads();
    if (t < 128) {
      int nd = t >> 6, o = t & 63;
      out[(size_t)(n0 + nd) * 64 + o] = bl[o] + pp[nd * 64 + o] + pp[128 + nd * 64 + o];
    }
  }
}

extern "C" void kernel_launch(void* const* d_in, const int* in_sizes, int n_in,
                              void* d_out, int out_size, void* d_ws, size_t ws_size,
                              hipStream_t stream) {
  const float* x  = (const float*)d_in[0];
  const float* H  = (const float*)d_in[1];
  const float* W1 = (const float*)d_in[2];
  const float* b1 = (const float*)d_in[3];
  const float* W2 = (const float*)d_in[4];
  const float* b2 = (const float*)d_in[5];
  const float* Wl = (const float*)d_in[6];
  const float* bl = (const float*)d_in[7];
  float* out = (float*)d_out;

  char* wsb = (char*)d_ws;
  float* dn   = (float*)wsb;  wsb += NN * 4;
  float* de   = (float*)wsb;  wsb += EE * 4;
  int*   cnt  = (int*)wsb;    wsb += NN * 4;
  int*   ccnt = (int*)wsb;    wsb += EE * 4;
  float* npb  = (float*)wsb;  wsb += (size_t)NN * 128 * 4;
  float* epb  = (float*)wsb;  wsb += (size_t)EE * 128 * 4;
  float* w    = (float*)wsb;  wsb += (size_t)EE * 64 * 4;
  ushortt* elist = (ushortt*)wsb; wsb += (size_t)NN * 128 * 2;
  ushortt* clist = (ushortt*)wsb; wsb += (size_t)EE * 192 * 2;

  hipLaunchKernelGGL(k_fused, dim3(NBLK), dim3(256), 0, stream,
                     H, x, W1, b1, W2, b2, Wl, bl,
                     elist, cnt, dn, clist, ccnt, de, npb, epb, w, out);
}

// Round 12
// 60.233 us; speedup vs baseline: 12.1593x; 12.1593x over previous
//
#include <hip/hip_runtime.h>
#include <math.h>

#define NN 2048
#define EE 1024

typedef unsigned long long ull;
typedef unsigned short ushortt;

// ---------------------------------------------------------------------------
// D1 k_scan (grid 1792): three jobs by block range (R10's layout, unchanged).
//   [0,1024)     cscan : block per edge col; 4 waves x 512-row segments
//   [1024,1536)  rfill : wave per node row -> elist[n][128], cnt[n], dn[n]
//   [1536,1792)  npb   : node projection npb = x @ W1[:, :64]^T + b1
// ---------------------------------------------------------------------------
__global__ void k_scan(const float* __restrict__ H, const float* __restrict__ x,
                       const float* __restrict__ W1, const float* __restrict__ b1,
                       ushortt* __restrict__ elist, int* __restrict__ cnt,
                       float* __restrict__ dn,
                       ushortt* __restrict__ clist, int* __restrict__ ccnt,
                       float* __restrict__ de,
                       float* __restrict__ npb) {
  __shared__ __align__(16) float smem[64 * 129 + 8 * 64];
  __shared__ ushortt cbuf[4][128];
  __shared__ int csh[4];
  int bid = blockIdx.x, t = threadIdx.x, wv = t >> 6, lane = t & 63;
  if (bid < 1024) {
    int e = bid;
    int count = 0;
    int r0 = wv * 512;
    #pragma unroll
    for (int i = 0; i < 8; ++i) {
      int r = r0 + i * 64 + lane;
      float hv = H[(size_t)r * EE + e];
      ull m = __ballot(hv != 0.f);
      int pos = count + __popcll(m & ((1ull << lane) - 1ull));
      if (hv != 0.f && pos < 128) cbuf[wv][pos] = (ushortt)r;
      count += __popcll(m);
    }
    if (lane == 0) csh[wv] = count;
    __syncthreads();
    int base = 0;
    #pragma unroll
    for (int u = 0; u < 4; ++u) base += (u < wv) ? min(csh[u], 128) : 0;
    int total = csh[0] + csh[1] + csh[2] + csh[3];
    int myc = min(count, 128);
    for (int i = lane; i < myc; i += 64) {
      int p = base + i;
      if (p < 192) clist[e * 192 + p] = cbuf[wv][i];
    }
    if (t == 0) {
      ccnt[e] = total;
      de[e] = total ? 1.f / (float)total : 0.f;
    }
  } else if (bid < 1536) {
    int n = (bid - 1024) * 4 + wv;
    const float* row = H + (size_t)n * EE;
    int count = 0;
    for (int i = 0; i < EE; i += 64) {
      float hv = row[i + lane];
      ull m = __ballot(hv != 0.f);
      int pos = count + __popcll(m & ((1ull << lane) - 1ull));
      if (hv != 0.f && pos < 128) elist[n * 128 + pos] = (ushortt)(i + lane);
      count += __popcll(m);
    }
    if (lane == 0) {
      cnt[n] = count;
      dn[n] = count ? rsqrtf((float)count) : 0.f;
    }
  } else {
    float* Wt = smem;
    float* xl = smem + 64 * 129;
    int b = bid - 1536;
    int r0 = b * 8;
    #pragma unroll
    for (int p = 0; p < 32; ++p) {
      int j = t + p * 256;
      int h = j >> 6, d = j & 63;
      Wt[d * 129 + h] = W1[h * 128 + d];
    }
    {
      int r = t >> 6, d = t & 63;
      xl[(r + 0) * 64 + d] = x[(size_t)(r0 + r) * 64 + d];
      xl[(r + 4) * 64 + d] = x[(size_t)(r0 + r + 4) * 64 + d];
    }
    __syncthreads();
    #pragma unroll
    for (int k = 0; k < 4; ++k) {
      int idx = t + k * 256;
      int row = idx >> 7, h = idx & 127;
      float acc = b1[h];
      #pragma unroll 8
      for (int d = 0; d < 64; ++d)
        acc += xl[row * 64 + d] * Wt[d * 129 + h];
      npb[(size_t)(r0 + row) * 128 + h] = acc;
    }
  }
}

// ---------------------------------------------------------------------------
// D2 k_edge (grid EE): ef gather + projection + BATCHED col scores + w.
// Scores: 256 threads = 64 entries x 4 subs (32 h each), 2-step shfl only --
// no 64-wide reduce chains; 64 independent score loads in flight.
// ---------------------------------------------------------------------------
__global__ void k_edge(const ushortt* __restrict__ clist,
                       const int* __restrict__ ccnt, const float* __restrict__ de,
                       const float* __restrict__ dn, const float* __restrict__ x,
                       const float* __restrict__ W1, const float* __restrict__ npb,
                       const float* __restrict__ W2, const float* __restrict__ b2,
                       float* __restrict__ epb, float* __restrict__ w) {
  __shared__ __align__(16) float Wt[64 * 129];   // 33024 B
  __shared__ __align__(16) float psum[4][64];
  __shared__ __align__(16) float efl[64];
  __shared__ __align__(16) float epl[128];
  __shared__ __align__(16) float pp[2][128];
  __shared__ __align__(16) float w2l[128];
  __shared__ __align__(16) float sval[192];
  __shared__ __align__(16) ushortt cls[192];
  int t = threadIdx.x, wv = t >> 6, lane = t & 63;
  int e = blockIdx.x;
  int c = min(ccnt[e], 192);
  // stage W1 edge-half (transposed), W2, clist entries
  #pragma unroll
  for (int p = 0; p < 32; ++p) {
    int j = t + p * 256;
    int h = j >> 6, d = j & 63;
    Wt[d * 129 + h] = W1[h * 128 + 64 + d];
  }
  if (t < 128) w2l[t] = W2[t];
  if (t < 96) ((uint*)cls)[t] = ((const uint*)(clist + (size_t)e * 192))[t];
  __syncthreads();
  // pass 1: ef gather (wave-strided entries, coalesced x rows)
  float acc = 0.f;
  for (int j = wv; j < c; j += 4) {
    int n = cls[j];
    acc += x[(size_t)n * 64 + lane];
  }
  psum[wv][lane] = acc;
  __syncthreads();
  if (wv == 0)
    efl[lane] = psum[0][lane] + psum[1][lane] + psum[2][lane] + psum[3][lane];
  __syncthreads();
  // projection: 256 threads = 128 h x 2 d-halves
  {
    int h = t & 127, hf = t >> 7;
    float a = 0.f;
    #pragma unroll 8
    for (int d = hf * 32; d < hf * 32 + 32; ++d)
      a += efl[d] * Wt[d * 129 + h];
    pp[hf][h] = a;
  }
  __syncthreads();
  if (t < 128) {
    float v = pp[0][t] + pp[1][t];
    epl[t] = v;
    epb[(size_t)e * 128 + t] = v;
  }
  __syncthreads();
  // batched scores: 64 entries/batch, 4 subs each covering 32 of 128 h
  {
    int sub = t & 3, jloc = t >> 2;   // jloc 0..63
    float b2v = b2[0];
    int nb = (c + 63) >> 6;
    for (int b = 0; b < nb; ++b) {
      int j = b * 64 + jloc;
      if (j < c) {
        int n = cls[j];
        const float* npr = npb + (size_t)n * 128;
        float a = 0.f;
        #pragma unroll
        for (int q = 0; q < 8; ++q) {
          int o = q * 16 + sub * 4;
          float4 av = *(const float4*)&npr[o];
          float4 ev = *(const float4*)&epl[o];
          float4 w2 = *(const float4*)&w2l[o];
          a += fmaxf(av.x + ev.x, 0.f) * w2.x + fmaxf(av.y + ev.y, 0.f) * w2.y
             + fmaxf(av.z + ev.z, 0.f) * w2.z + fmaxf(av.w + ev.w, 0.f) * w2.w;
        }
        a += __shfl_xor(a, 1, 64);
        a += __shfl_xor(a, 2, 64);
        if (sub == 0)
          sval[j] = dn[n] / (1.f + __expf(-(a + b2v)));
      }
    }
  }
  __syncthreads();
  // pass 2: weighted gather, coefficients from LDS, x rows L1-warm
  float accw = 0.f;
  for (int j = wv; j < c; j += 4) {
    int n = cls[j];
    accw += sval[j] * x[(size_t)n * 64 + lane];
  }
  psum[wv][lane] = accw;
  __syncthreads();
  if (wv == 0)
    w[(size_t)e * 64 + lane] =
        de[e] * (psum[0][lane] + psum[1][lane] + psum[2][lane] + psum[3][lane]);
}

// ---------------------------------------------------------------------------
// D3 k_node (grid NN): BATCHED row scores + z gather + final linear.
// ---------------------------------------------------------------------------
__global__ void k_node(const ushortt* __restrict__ elist, const int* __restrict__ cnt,
                       const float* __restrict__ dn, const float* __restrict__ npb,
                       const float* __restrict__ epb, const float* __restrict__ W2,
                       const float* __restrict__ b2, const float* __restrict__ w,
                       const float* __restrict__ Wlg, const float* __restrict__ bl,
                       float* __restrict__ out) {
  __shared__ __align__(16) float Wlds[64 * 65];  // 16640 B
  __shared__ __align__(16) float npl[128];
  __shared__ __align__(16) float w2l[128];
  __shared__ __align__(16) float sval[128];
  __shared__ __align__(16) float psum[4][64];
  __shared__ __align__(16) float zl[64];
  __shared__ __align__(16) ushortt els[128];
  int t = threadIdx.x, wv = t >> 6, lane = t & 63;
  int n = blockIdx.x;
  int c = min(cnt[n], 128);
  #pragma unroll
  for (int p = 0; p < 17; ++p) {
    int j = t + p * 256;
    if (j < 4160) Wlds[j] = Wlg[(j / 65) * 64 + (j % 65)];  // guard pad column
  }
  // simpler correct staging of Wl (64x64 -> padded 65): redo cleanly below
  __syncthreads();
  #pragma unroll
  for (int p = 0; p < 16; ++p) {
    int j = t + p * 256;
    Wlds[(j >> 6) * 65 + (j & 63)] = Wlg[j];
  }
  if (t < 128) npl[t] = npb[(size_t)n * 128 + t];
  if (t >= 128 && t < 256) w2l[t - 128] = W2[t - 128];
  if (t < 64) ((uint*)els)[t] = ((const uint*)(elist + (size_t)n * 128))[t];
  __syncthreads();
  // batched scores: 64 entries/batch x 4 subs
  {
    int sub = t & 3, jloc = t >> 2;
    float b2v = b2[0];
    int nb = (c + 63) >> 6;
    for (int b = 0; b < nb; ++b) {
      int j = b * 64 + jloc;
      if (j < c) {
        int e = els[j];
        const float* epr = epb + (size_t)e * 128;
        float a = 0.f;
        #pragma unroll
        for (int q = 0; q < 8; ++q) {
          int o = q * 16 + sub * 4;
          float4 ev = *(const float4*)&epr[o];
          float4 nv = *(const float4*)&npl[o];
          float4 w2 = *(const float4*)&w2l[o];
          a += fmaxf(nv.x + ev.x, 0.f) * w2.x + fmaxf(nv.y + ev.y, 0.f) * w2.y
             + fmaxf(nv.z + ev.z, 0.f) * w2.z + fmaxf(nv.w + ev.w, 0.f) * w2.w;
        }
        a += __shfl_xor(a, 1, 64);
        a += __shfl_xor(a, 2, 64);
        if (sub == 0)
          sval[j] = 1.f / (1.f + __expf(-(a + b2v)));
      }
    }
  }
  __syncthreads();
  // z gather: coefficients from LDS, w rows from L2
  float acc = 0.f;
  for (int j = wv; j < c; j += 4) {
    int e = els[j];
    acc += sval[j] * w[(size_t)e * 64 + lane];
  }
  psum[wv][lane] = acc;
  __syncthreads();
  if (wv == 0)
    zl[lane] = dn[n] * (psum[0][lane] + psum[1][lane] + psum[2][lane] + psum[3][lane]);
  __syncthreads();
  // final linear: o = lane, wave wv covers d-quarter
  {
    float po = 0.f;
    #pragma unroll
    for (int d = wv * 16; d < wv * 16 + 16; ++d)
      po += zl[d] * Wlds[lane * 65 + d];
    psum[wv][lane] = po;
  }
  __syncthreads();
  if (wv == 0)
    out[(size_t)n * 64 + lane] =
        bl[lane] + psum[0][lane] + psum[1][lane] + psum[2][lane] + psum[3][lane];
}

extern "C" void kernel_launch(void* const* d_in, const int* in_sizes, int n_in,
                              void* d_out, int out_size, void* d_ws, size_t ws_size,
                              hipStream_t stream) {
  const float* x  = (const float*)d_in[0];
  const float* H  = (const float*)d_in[1];
  const float* W1 = (const float*)d_in[2];
  const float* b1 = (const float*)d_in[3];
  const float* W2 = (const float*)d_in[4];
  const float* b2 = (const float*)d_in[5];
  const float* Wl = (const float*)d_in[6];
  const float* bl = (const float*)d_in[7];
  float* out = (float*)d_out;

  char* wsb = (char*)d_ws;
  float* dn   = (float*)wsb;  wsb += NN * 4;
  float* de   = (float*)wsb;  wsb += EE * 4;
  int*   cnt  = (int*)wsb;    wsb += NN * 4;
  int*   ccnt = (int*)wsb;    wsb += EE * 4;
  float* npb  = (float*)wsb;  wsb += (size_t)NN * 128 * 4;
  float* epb  = (float*)wsb;  wsb += (size_t)EE * 128 * 4;
  float* w    = (float*)wsb;  wsb += (size_t)EE * 64 * 4;
  ushortt* elist = (ushortt*)wsb; wsb += (size_t)NN * 128 * 2;
  ushortt* clist = (ushortt*)wsb; wsb += (size_t)EE * 192 * 2;

  hipLaunchKernelGGL(k_scan, dim3(1792), dim3(256), 0, stream,
                     H, x, W1, b1, elist, cnt, dn, clist, ccnt, de, npb);
  hipLaunchKernelGGL(k_edge, dim3(EE), dim3(256), 0, stream,
                     clist, ccnt, de, dn, x, W1, npb, W2, b2, epb, w);
  hipLaunchKernelGGL(k_node, dim3(NN), dim3(256), 0, stream,
                     elist, cnt, dn, npb, epb, W2, b2, w, Wl, bl, out);
}

// Round 14
// 54.688 us; speedup vs baseline: 13.3922x; 1.1014x over previous
//
#include <hip/hip_runtime.h>
#include <math.h>

#define NN 2048
#define EE 1024

typedef unsigned long long ull;
typedef unsigned short ushortt;

// ---------------------------------------------------------------------------
// D1 k_scan (grid 1792): three jobs by block range (unchanged from R12).
//   [0,1024)     cscan : block per edge col; 4 waves x 512-row segments
//   [1024,1536)  rfill : wave per node row -> elist[n][128], cnt[n], dn[n]
//   [1536,1792)  npb   : node projection npb = x @ W1[:, :64]^T + b1
// ---------------------------------------------------------------------------
__global__ void k_scan(const float* __restrict__ H, const float* __restrict__ x,
                       const float* __restrict__ W1, const float* __restrict__ b1,
                       ushortt* __restrict__ elist, int* __restrict__ cnt,
                       float* __restrict__ dn,
                       ushortt* __restrict__ clist, int* __restrict__ ccnt,
                       float* __restrict__ de,
                       float* __restrict__ npb) {
  __shared__ __align__(16) float smem[64 * 129 + 8 * 64];
  __shared__ ushortt cbuf[4][128];
  __shared__ int csh[4];
  int bid = blockIdx.x, t = threadIdx.x, wv = t >> 6, lane = t & 63;
  if (bid < 1024) {
    int e = bid;
    int count = 0;
    int r0 = wv * 512;
    #pragma unroll
    for (int i = 0; i < 8; ++i) {
      int r = r0 + i * 64 + lane;
      float hv = H[(size_t)r * EE + e];
      ull m = __ballot(hv != 0.f);
      int pos = count + __popcll(m & ((1ull << lane) - 1ull));
      if (hv != 0.f && pos < 128) cbuf[wv][pos] = (ushortt)r;
      count += __popcll(m);
    }
    if (lane == 0) csh[wv] = count;
    __syncthreads();
    int base = 0;
    #pragma unroll
    for (int u = 0; u < 4; ++u) base += (u < wv) ? min(csh[u], 128) : 0;
    int total = csh[0] + csh[1] + csh[2] + csh[3];
    int myc = min(count, 128);
    for (int i = lane; i < myc; i += 64) {
      int p = base + i;
      if (p < 192) clist[e * 192 + p] = cbuf[wv][i];
    }
    if (t == 0) {
      ccnt[e] = total;
      de[e] = total ? 1.f / (float)total : 0.f;
    }
  } else if (bid < 1536) {
    int n = (bid - 1024) * 4 + wv;
    const float* row = H + (size_t)n * EE;
    int count = 0;
    for (int i = 0; i < EE; i += 64) {
      float hv = row[i + lane];
      ull m = __ballot(hv != 0.f);
      int pos = count + __popcll(m & ((1ull << lane) - 1ull));
      if (hv != 0.f && pos < 128) elist[n * 128 + pos] = (ushortt)(i + lane);
      count += __popcll(m);
    }
    if (lane == 0) {
      cnt[n] = count;
      dn[n] = count ? rsqrtf((float)count) : 0.f;
    }
  } else {
    float* Wt = smem;
    float* xl = smem + 64 * 129;
    int b = bid - 1536;
    int r0 = b * 8;
    #pragma unroll
    for (int p = 0; p < 32; ++p) {
      int j = t + p * 256;
      int h = j >> 6, d = j & 63;
      Wt[d * 129 + h] = W1[h * 128 + d];
    }
    {
      int r = t >> 6, d = t & 63;
      xl[(r + 0) * 64 + d] = x[(size_t)(r0 + r) * 64 + d];
      xl[(r + 4) * 64 + d] = x[(size_t)(r0 + r + 4) * 64 + d];
    }
    __syncthreads();
    #pragma unroll
    for (int k = 0; k < 4; ++k) {
      int idx = t + k * 256;
      int row = idx >> 7, h = idx & 127;
      float acc = b1[h];
      #pragma unroll 8
      for (int d = 0; d < 64; ++d)
        acc += xl[row * 64 + d] * Wt[d * 129 + h];
      npb[(size_t)(r0 + row) * 128 + h] = acc;
    }
  }
}

// ---------------------------------------------------------------------------
// D2 k_edge (grid EE): ef gather + projection (LDS-only epl) + batched col
// scores + w.  Bridge: raw sigma written CONTIGUOUSLY to svc[e*192+j] --
// every 64B line belongs to exactly one block (no cross-XCD false sharing,
// the R13 failure mode).
// ---------------------------------------------------------------------------
__global__ void k_edge(const ushortt* __restrict__ clist,
                       const int* __restrict__ ccnt, const float* __restrict__ de,
                       const float* __restrict__ dn, const float* __restrict__ x,
                       const float* __restrict__ W1, const float* __restrict__ npb,
                       const float* __restrict__ W2, const float* __restrict__ b2,
                       float* __restrict__ svc, float* __restrict__ w) {
  __shared__ __align__(16) float Wt[64 * 129];   // 33024 B
  __shared__ __align__(16) float psum[4][64];
  __shared__ __align__(16) float efl[64];
  __shared__ __align__(16) float epl[128];
  __shared__ __align__(16) float pp[2][128];
  __shared__ __align__(16) float w2l[128];
  __shared__ __align__(16) float sval[192];
  __shared__ __align__(16) ushortt cls[192];
  int t = threadIdx.x, wv = t >> 6, lane = t & 63;
  int e = blockIdx.x;
  int c = min(ccnt[e], 192);
  #pragma unroll
  for (int p = 0; p < 32; ++p) {
    int j = t + p * 256;
    int h = j >> 6, d = j & 63;
    Wt[d * 129 + h] = W1[h * 128 + 64 + d];
  }
  if (t < 128) w2l[t] = W2[t];
  if (t < 96) ((uint*)cls)[t] = ((const uint*)(clist + (size_t)e * 192))[t];
  __syncthreads();
  // pass 1: ef gather (wave-strided entries, coalesced x rows)
  float acc = 0.f;
  for (int j = wv; j < c; j += 4) {
    int n = cls[j];
    acc += x[(size_t)n * 64 + lane];
  }
  psum[wv][lane] = acc;
  __syncthreads();
  if (wv == 0)
    efl[lane] = psum[0][lane] + psum[1][lane] + psum[2][lane] + psum[3][lane];
  __syncthreads();
  // projection: 256 threads = 128 h x 2 d-halves
  {
    int h = t & 127, hf = t >> 7;
    float a = 0.f;
    #pragma unroll 8
    for (int d = hf * 32; d < hf * 32 + 32; ++d)
      a += efl[d] * Wt[d * 129 + h];
    pp[hf][h] = a;
  }
  __syncthreads();
  if (t < 128) epl[t] = pp[0][t] + pp[1][t];
  __syncthreads();
  // batched scores: 64 entries x 4 subs (32 h each); sigma -> svc (contiguous)
  {
    int sub = t & 3, jloc = t >> 2;
    float b2v = b2[0];
    int nb = (c + 63) >> 6;
    for (int b = 0; b < nb; ++b) {
      int j = b * 64 + jloc;
      if (j < c) {
        int n = cls[j];
        const float* npr = npb + (size_t)n * 128;
        float a = 0.f;
        #pragma unroll
        for (int q = 0; q < 8; ++q) {
          int o = q * 16 + sub * 4;
          float4 av = *(const float4*)&npr[o];
          float4 ev = *(const float4*)&epl[o];
          float4 w2 = *(const float4*)&w2l[o];
          a += fmaxf(av.x + ev.x, 0.f) * w2.x + fmaxf(av.y + ev.y, 0.f) * w2.y
             + fmaxf(av.z + ev.z, 0.f) * w2.z + fmaxf(av.w + ev.w, 0.f) * w2.w;
        }
        a += __shfl_xor(a, 1, 64);
        a += __shfl_xor(a, 2, 64);
        if (sub == 0) {
          float sg = 1.f / (1.f + __expf(-(a + b2v)));
          sval[j] = dn[n] * sg;                 // local use (w reduction)
          svc[(size_t)e * 192 + j] = sg;        // bridge, block-local lines
        }
      }
    }
  }
  __syncthreads();
  // pass 2: weighted gather
  float accw = 0.f;
  for (int j = wv; j < c; j += 4) {
    int n = cls[j];
    accw += sval[j] * x[(size_t)n * 64 + lane];
  }
  psum[wv][lane] = accw;
  __syncthreads();
  if (wv == 0)
    w[(size_t)e * 64 + lane] =
        de[e] * (psum[0][lane] + psum[1][lane] + psum[2][lane] + psum[3][lane]);
}

// ---------------------------------------------------------------------------
// D3 k_node (grid NN): sigma recovered by BINARY SEARCH of n in the sorted
// clist[e] (8 dependent 2B loads, one thread per entry, reads only -- no
// scatter, no score recompute, no epb).  Then z gather + final linear.
// ---------------------------------------------------------------------------
__global__ void k_node(const ushortt* __restrict__ elist, const int* __restrict__ cnt,
                       const float* __restrict__ dn,
                       const ushortt* __restrict__ clist, const int* __restrict__ ccnt,
                       const float* __restrict__ svc, const float* __restrict__ w,
                       const float* __restrict__ Wlg, const float* __restrict__ bl,
                       float* __restrict__ out) {
  __shared__ __align__(16) float Wlds[64 * 65];  // 16640 B
  __shared__ __align__(16) float sval[128];
  __shared__ __align__(16) float psum[4][64];
  __shared__ __align__(16) float zl[64];
  __shared__ __align__(16) ushortt els[128];
  int t = threadIdx.x, wv = t >> 6, lane = t & 63;
  int n = blockIdx.x;
  int c = min(cnt[n], 128);
  #pragma unroll
  for (int p = 0; p < 16; ++p) {
    int j = t + p * 256;
    Wlds[(j >> 6) * 65 + (j & 63)] = Wlg[j];
  }
  if (t < 64) ((uint*)els)[t] = ((const uint*)(elist + (size_t)n * 128))[t];
  __syncthreads();
  if (t < c) {
    int e = els[t];
    const ushortt* cl = clist + (size_t)e * 192;
    int lo = 0, hi = min(ccnt[e], 192);
    while (lo < hi) {            // <=8 iterations; entry is guaranteed present
      int mid = (lo + hi) >> 1;
      if (cl[mid] < n) lo = mid + 1; else hi = mid;
    }
    sval[t] = svc[(size_t)e * 192 + lo];
  }
  __syncthreads();
  // z gather: coefficients from LDS, w rows from L2
  float acc = 0.f;
  for (int j = wv; j < c; j += 4) {
    int e = els[j];
    acc += sval[j] * w[(size_t)e * 64 + lane];
  }
  psum[wv][lane] = acc;
  __syncthreads();
  if (wv == 0)
    zl[lane] = dn[n] * (psum[0][lane] + psum[1][lane] + psum[2][lane] + psum[3][lane]);
  __syncthreads();
  // final linear: o = lane, wave wv covers a d-quarter
  {
    float po = 0.f;
    #pragma unroll
    for (int d = wv * 16; d < wv * 16 + 16; ++d)
      po += zl[d] * Wlds[lane * 65 + d];
    psum[wv][lane] = po;
  }
  __syncthreads();
  if (wv == 0)
    out[(size_t)n * 64 + lane] =
        bl[lane] + psum[0][lane] + psum[1][lane] + psum[2][lane] + psum[3][lane];
}

extern "C" void kernel_launch(void* const* d_in, const int* in_sizes, int n_in,
                              void* d_out, int out_size, void* d_ws, size_t ws_size,
                              hipStream_t stream) {
  const float* x  = (const float*)d_in[0];
  const float* H  = (const float*)d_in[1];
  const float* W1 = (const float*)d_in[2];
  const float* b1 = (const float*)d_in[3];
  const float* W2 = (const float*)d_in[4];
  const float* b2 = (const float*)d_in[5];
  const float* Wl = (const float*)d_in[6];
  const float* bl = (const float*)d_in[7];
  float* out = (float*)d_out;

  char* wsb = (char*)d_ws;
  float* dn   = (float*)wsb;  wsb += NN * 4;
  float* de   = (float*)wsb;  wsb += EE * 4;
  int*   cnt  = (int*)wsb;    wsb += NN * 4;
  int*   ccnt = (int*)wsb;    wsb += EE * 4;
  float* npb  = (float*)wsb;  wsb += (size_t)NN * 128 * 4;
  float* w    = (float*)wsb;  wsb += (size_t)EE * 64 * 4;
  float* svc  = (float*)wsb;  wsb += (size_t)EE * 192 * 4;
  ushortt* elist = (ushortt*)wsb; wsb += (size_t)NN * 128 * 2;
  ushortt* clist = (ushortt*)wsb; wsb += (size_t)EE * 192 * 2;

  hipLaunchKernelGGL(k_scan, dim3(1792), dim3(256), 0, stream,
                     H, x, W1, b1, elist, cnt, dn, clist, ccnt, de, npb);
  hipLaunchKernelGGL(k_edge, dim3(EE), dim3(256), 0, stream,
                     clist, ccnt, de, dn, x, W1, npb, W2, b2, svc, w);
  hipLaunchKernelGGL(k_node, dim3(NN), dim3(256), 0, stream,
                     elist, cnt, dn, clist, ccnt, svc, w, Wl, bl, out);
}

// Round 15
// 51.443 us; speedup vs baseline: 14.2369x; 1.0631x over previous
//
#include <hip/hip_runtime.h>
#include <math.h>

#define NN 2048
#define EE 1024

typedef unsigned long long ull;
typedef unsigned short ushortt;

// ---------------------------------------------------------------------------
// D1 k_scan (grid 1024): three jobs by block range.
//   [0,256)    cscan : 4 cols/block via float4 loads (line-touches /4);
//                      4 waves x 512-row segments, LDS merge -> clist/ccnt/de
//   [256,768)  rfill : wave per node row -> elist[n][128], cnt[n], dn[n]
//   [768,1024) npb   : node projection npb = x @ W1[:, :64]^T + b1
// ---------------------------------------------------------------------------
__global__ void k_scan(const float* __restrict__ H, const float* __restrict__ x,
                       const float* __restrict__ W1, const float* __restrict__ b1,
                       ushortt* __restrict__ elist, int* __restrict__ cnt,
                       float* __restrict__ dn,
                       ushortt* __restrict__ clist, int* __restrict__ ccnt,
                       float* __restrict__ de,
                       float* __restrict__ npb) {
  __shared__ __align__(16) float smem[64 * 129 + 8 * 64];
  __shared__ ushortt cbuf[4][4][128];   // [wave][col][pos]
  __shared__ int csh[4][4];             // [wave][col]
  int bid = blockIdx.x, t = threadIdx.x, wv = t >> 6, lane = t & 63;
  if (bid < 256) {
    // ---- cscan: 4 columns per block; wave wv scans rows [wv*512, wv*512+512)
    int e0 = bid * 4;
    int count[4] = {0, 0, 0, 0};
    int r0 = wv * 512;
    #pragma unroll
    for (int i = 0; i < 8; ++i) {
      int r = r0 + i * 64 + lane;
      float4 hv = *(const float4*)&H[(size_t)r * EE + e0];
      float va[4] = {hv.x, hv.y, hv.z, hv.w};
      #pragma unroll
      for (int col = 0; col < 4; ++col) {
        ull m = __ballot(va[col] != 0.f);
        int pos = count[col] + __popcll(m & ((1ull << lane) - 1ull));
        if (va[col] != 0.f && pos < 128) cbuf[wv][col][pos] = (ushortt)r;
        count[col] += __popcll(m);
      }
    }
    if (lane == 0) {
      #pragma unroll
      for (int col = 0; col < 4; ++col) csh[wv][col] = count[col];
    }
    __syncthreads();
    // merge: wave wv owns column wv
    {
      int col = wv;
      int e = e0 + col;
      int base = 0;
      #pragma unroll
      for (int u = 0; u < 4; ++u) {
        int cc = min(csh[u][col], 128);
        for (int i = lane; i < cc; i += 64) {
          int p = base + i;
          if (p < 192) clist[e * 192 + p] = cbuf[u][col][i];
        }
        base += cc;
      }
      if (lane == 0) {
        int total = csh[0][col] + csh[1][col] + csh[2][col] + csh[3][col];
        ccnt[e] = total;
        de[e] = total ? 1.f / (float)total : 0.f;
      }
    }
  } else if (bid < 768) {
    // ---- rfill (coalesced row scans), 4 rows per block
    int n = (bid - 256) * 4 + wv;
    const float* row = H + (size_t)n * EE;
    int count = 0;
    for (int i = 0; i < EE; i += 64) {
      float hv = row[i + lane];
      ull m = __ballot(hv != 0.f);
      int pos = count + __popcll(m & ((1ull << lane) - 1ull));
      if (hv != 0.f && pos < 128) elist[n * 128 + pos] = (ushortt)(i + lane);
      count += __popcll(m);
    }
    if (lane == 0) {
      cnt[n] = count;
      dn[n] = count ? rsqrtf((float)count) : 0.f;
    }
  } else {
    // ---- npb: 8 rows x 128 h per block; W1 node-half transposed in LDS
    float* Wt = smem;
    float* xl = smem + 64 * 129;
    int b = bid - 768;
    int r0 = b * 8;
    #pragma unroll
    for (int p = 0; p < 32; ++p) {
      int j = t + p * 256;
      int h = j >> 6, d = j & 63;
      Wt[d * 129 + h] = W1[h * 128 + d];
    }
    {
      int r = t >> 6, d = t & 63;
      xl[(r + 0) * 64 + d] = x[(size_t)(r0 + r) * 64 + d];
      xl[(r + 4) * 64 + d] = x[(size_t)(r0 + r + 4) * 64 + d];
    }
    __syncthreads();
    #pragma unroll
    for (int k = 0; k < 4; ++k) {
      int idx = t + k * 256;
      int row = idx >> 7, h = idx & 127;
      float acc = b1[h];
      #pragma unroll 8
      for (int d = 0; d < 64; ++d)
        acc += xl[row * 64 + d] * Wt[d * 129 + h];
      npb[(size_t)(r0 + row) * 128 + h] = acc;
    }
  }
}

// ---------------------------------------------------------------------------
// D2 k_edge (grid EE): ef gather + projection (LDS epl) + batched col scores
// + w.  Sigma bridge written contiguously to svc[e*192+j] (block-local lines
// only -- R13 lesson: never share a 64B line across writer blocks).
// ---------------------------------------------------------------------------
__global__ void k_edge(const ushortt* __restrict__ clist,
                       const int* __restrict__ ccnt, const float* __restrict__ de,
                       const float* __restrict__ dn, const float* __restrict__ x,
                       const float* __restrict__ W1, const float* __restrict__ npb,
                       const float* __restrict__ W2, const float* __restrict__ b2,
                       float* __restrict__ svc, float* __restrict__ w) {
  __shared__ __align__(16) float Wt[64 * 129];   // 33024 B
  __shared__ __align__(16) float psum[4][64];
  __shared__ __align__(16) float efl[64];
  __shared__ __align__(16) float epl[128];
  __shared__ __align__(16) float pp[2][128];
  __shared__ __align__(16) float w2l[128];
  __shared__ __align__(16) float sval[192];
  __shared__ __align__(16) ushortt cls[192];
  int t = threadIdx.x, wv = t >> 6, lane = t & 63;
  int e = blockIdx.x;
  int c = min(ccnt[e], 192);
  #pragma unroll
  for (int p = 0; p < 32; ++p) {
    int j = t + p * 256;
    int h = j >> 6, d = j & 63;
    Wt[d * 129 + h] = W1[h * 128 + 64 + d];
  }
  if (t < 128) w2l[t] = W2[t];
  if (t < 96) ((uint*)cls)[t] = ((const uint*)(clist + (size_t)e * 192))[t];
  __syncthreads();
  // pass 1: ef gather (wave-strided entries, coalesced x rows)
  float acc = 0.f;
  for (int j = wv; j < c; j += 4) {
    int n = cls[j];
    acc += x[(size_t)n * 64 + lane];
  }
  psum[wv][lane] = acc;
  __syncthreads();
  if (wv == 0)
    efl[lane] = psum[0][lane] + psum[1][lane] + psum[2][lane] + psum[3][lane];
  __syncthreads();
  // projection: 256 threads = 128 h x 2 d-halves
  {
    int h = t & 127, hf = t >> 7;
    float a = 0.f;
    #pragma unroll 8
    for (int d = hf * 32; d < hf * 32 + 32; ++d)
      a += efl[d] * Wt[d * 129 + h];
    pp[hf][h] = a;
  }
  __syncthreads();
  if (t < 128) epl[t] = pp[0][t] + pp[1][t];
  __syncthreads();
  // batched scores: 64 entries x 4 subs (32 h each); sigma -> svc (contiguous)
  {
    int sub = t & 3, jloc = t >> 2;
    float b2v = b2[0];
    int nb = (c + 63) >> 6;
    for (int b = 0; b < nb; ++b) {
      int j = b * 64 + jloc;
      if (j < c) {
        int n = cls[j];
        const float* npr = npb + (size_t)n * 128;
        float a = 0.f;
        #pragma unroll
        for (int q = 0; q < 8; ++q) {
          int o = q * 16 + sub * 4;
          float4 av = *(const float4*)&npr[o];
          float4 ev = *(const float4*)&epl[o];
          float4 w2 = *(const float4*)&w2l[o];
          a += fmaxf(av.x + ev.x, 0.f) * w2.x + fmaxf(av.y + ev.y, 0.f) * w2.y
             + fmaxf(av.z + ev.z, 0.f) * w2.z + fmaxf(av.w + ev.w, 0.f) * w2.w;
        }
        a += __shfl_xor(a, 1, 64);
        a += __shfl_xor(a, 2, 64);
        if (sub == 0) {
          float sg = 1.f / (1.f + __expf(-(a + b2v)));
          sval[j] = dn[n] * sg;                 // local use (w reduction)
          svc[(size_t)e * 192 + j] = sg;        // bridge, block-local lines
        }
      }
    }
  }
  __syncthreads();
  // pass 2: weighted gather
  float accw = 0.f;
  for (int j = wv; j < c; j += 4) {
    int n = cls[j];
    accw += sval[j] * x[(size_t)n * 64 + lane];
  }
  psum[wv][lane] = accw;
  __syncthreads();
  if (wv == 0)
    w[(size_t)e * 64 + lane] =
        de[e] * (psum[0][lane] + psum[1][lane] + psum[2][lane] + psum[3][lane]);
}

// ---------------------------------------------------------------------------
// D3 k_node (grid NN/2): 2 nodes per block (halves Wl staging traffic).
// sigma via binary search of n in sorted clist[e] (reads only); z gather
// 2 waves/node; final linear 2 nodes x 64 o x 2 d-halves.
// ---------------------------------------------------------------------------
__global__ void k_node(const ushortt* __restrict__ elist, const int* __restrict__ cnt,
                       const float* __restrict__ dn,
                       const ushortt* __restrict__ clist, const int* __restrict__ ccnt,
                       const float* __restrict__ svc, const float* __restrict__ w,
                       const float* __restrict__ Wlg, const float* __restrict__ bl,
                       float* __restrict__ out) {
  __shared__ __align__(16) float Wlds[64 * 65];  // 16640 B
  __shared__ __align__(16) float sval[2][128];
  __shared__ __align__(16) float psum[4][64];
  __shared__ __align__(16) float zl[2][64];
  __shared__ __align__(16) ushortt els[2][128];
  int t = threadIdx.x, wv = t >> 6, lane = t & 63;
  int n0 = blockIdx.x * 2;
  #pragma unroll
  for (int p = 0; p < 16; ++p) {
    int j = t + p * 256;
    Wlds[(j >> 6) * 65 + (j & 63)] = Wlg[j];
  }
  if (t < 128) ((uint*)els)[t] = ((const uint*)(elist + (size_t)n0 * 128))[t];
  __syncthreads();
  // sigma search: thread t covers node t>>7, entry t&127
  {
    int nd = t >> 7, jj = t & 127;
    int n = n0 + nd;
    int c = min(cnt[n], 128);
    if (jj < c) {
      int e = els[nd][jj];
      const ushortt* cl = clist + (size_t)e * 192;
      int lo = 0, hi = min(ccnt[e], 192);
      while (lo < hi) {          // <=8 iters; entry guaranteed present
        int mid = (lo + hi) >> 1;
        if (cl[mid] < n) lo = mid + 1; else hi = mid;
      }
      sval[nd][jj] = svc[(size_t)e * 192 + lo];
    }
  }
  __syncthreads();
  // z gather: waves (0,1) -> node 0, (2,3) -> node 1; j strided by 2
  {
    int nd = wv >> 1;
    int n = n0 + nd;
    int c = min(cnt[n], 128);
    float acc = 0.f;
    for (int j = wv & 1; j < c; j += 2) {
      int e = els[nd][j];
      acc += sval[nd][j] * w[(size_t)e * 64 + lane];
    }
    psum[wv][lane] = acc;
    __syncthreads();
    if ((wv & 1) == 0)
      zl[nd][lane] = dn[n] * (psum[wv][lane] + psum[wv + 1][lane]);
  }
  __syncthreads();
  // final linear: t = dh*128 + nd*64 + o  (psum reused as [2][128] scratch)
  {
    float* pp = (float*)psum;
    int o = t & 63, nd = (t >> 6) & 1, dh = t >> 7;
    float po = 0.f;
    #pragma unroll
    for (int d = dh * 32; d < dh * 32 + 32; ++d)
      po += zl[nd][d] * Wlds[o * 65 + d];
    pp[dh * 128 + nd * 64 + o] = po;
    __syncthreads();
    if (t < 128) {
      int ndo = t >> 6, oo = t & 63;
      out[(size_t)(n0 + ndo) * 64 + oo] = bl[oo] + pp[ndo * 64 + oo] + pp[128 + ndo * 64 + oo];
    }
  }
}

extern "C" void kernel_launch(void* const* d_in, const int* in_sizes, int n_in,
                              void* d_out, int out_size, void* d_ws, size_t ws_size,
                              hipStream_t stream) {
  const float* x  = (const float*)d_in[0];
  const float* H  = (const float*)d_in[1];
  const float* W1 = (const float*)d_in[2];
  const float* b1 = (const float*)d_in[3];
  const float* W2 = (const float*)d_in[4];
  const float* b2 = (const float*)d_in[5];
  const float* Wl = (const float*)d_in[6];
  const float* bl = (const float*)d_in[7];
  float* out = (float*)d_out;

  char* wsb = (char*)d_ws;
  float* dn   = (float*)wsb;  wsb += NN * 4;
  float* de   = (float*)wsb;  wsb += EE * 4;
  int*   cnt  = (int*)wsb;    wsb += NN * 4;
  int*   ccnt = (int*)wsb;    wsb += EE * 4;
  float* npb  = (float*)wsb;  wsb += (size_t)NN * 128 * 4;
  float* w    = (float*)wsb;  wsb += (size_t)EE * 64 * 4;
  float* svc  = (float*)wsb;  wsb += (size_t)EE * 192 * 4;
  ushortt* elist = (ushortt*)wsb; wsb += (size_t)NN * 128 * 2;
  ushortt* clist = (ushortt*)wsb; wsb += (size_t)EE * 192 * 2;

  hipLaunchKernelGGL(k_scan, dim3(1024), dim3(256), 0, stream,
                     H, x, W1, b1, elist, cnt, dn, clist, ccnt, de, npb);
  hipLaunchKernelGGL(k_edge, dim3(EE), dim3(256), 0, stream,
                     clist, ccnt, de, dn, x, W1, npb, W2, b2, svc, w);
  hipLaunchKernelGGL(k_node, dim3(NN / 2), dim3(256), 0, stream,
                     elist, cnt, dn, clist, ccnt, svc, w, Wl, bl, out);
}

// Round 16
// 48.249 us; speedup vs baseline: 15.1795x; 1.0662x over previous
//
#include <hip/hip_runtime.h>
#include <math.h>

#define NN 2048
#define EE 1024

typedef unsigned long long ull;
typedef unsigned short ushortt;

// ---------------------------------------------------------------------------
// D1 k_scan (grid 768 x 512 threads): three jobs by block range.
//   [0,256)    cscan : 4 cols/block via float4; 8 waves x 256-row segments
//   [256,512)  rfill : 8 rows/block, 1 row/wave, float4 (4 ballot rounds)
//   [512,768)  npb   : node projection npb = x @ W1[:, :64]^T + b1 (8 rows)
// ---------------------------------------------------------------------------
__global__ __launch_bounds__(512)
void k_scan(const float* __restrict__ H, const float* __restrict__ x,
            const float* __restrict__ W1, const float* __restrict__ b1,
            ushortt* __restrict__ elist, int* __restrict__ cnt,
            float* __restrict__ dn,
            ushortt* __restrict__ clist, int* __restrict__ ccnt,
            float* __restrict__ de,
            float* __restrict__ npb) {
  __shared__ __align__(16) float smem[64 * 129 + 8 * 64];
  __shared__ ushortt cbuf[8][4][64];    // [wave-segment][col][pos]
  __shared__ int csh[8][4];
  int bid = blockIdx.x, t = threadIdx.x, wv = t >> 6, lane = t & 63;
  ull below = (1ull << lane) - 1ull;
  if (bid < 256) {
    // ---- cscan: 4 cols/block; wave wv scans rows [wv*256, wv*256+256)
    int e0 = bid * 4;
    int cs[4] = {0, 0, 0, 0};
    #pragma unroll
    for (int it = 0; it < 4; ++it) {
      int r = wv * 256 + it * 64 + lane;
      float4 hv = *(const float4*)&H[(size_t)r * EE + e0];
      float va[4] = {hv.x, hv.y, hv.z, hv.w};
      #pragma unroll
      for (int col = 0; col < 4; ++col) {
        ull m = __ballot(va[col] != 0.f);
        int pos = cs[col] + __popcll(m & below);
        if (va[col] != 0.f && pos < 64) cbuf[wv][col][pos] = (ushortt)r;
        cs[col] += __popcll(m);
      }
    }
    if (lane == 0) {
      #pragma unroll
      for (int col = 0; col < 4; ++col) csh[wv][col] = cs[col];
    }
    __syncthreads();
    if (wv < 4) {   // wave wv merges column wv (segments already row-ascending)
      int col = wv, e = e0 + col;
      int base = 0, total = 0;
      #pragma unroll
      for (int u = 0; u < 8; ++u) {
        int cu = csh[u][col];
        int cc = min(cu, 64);
        for (int i = lane; i < cc; i += 64) {
          int p = base + i;
          if (p < 192) clist[e * 192 + p] = cbuf[u][col][i];
        }
        base += cc;
        total += cu;
      }
      if (lane == 0) {
        ccnt[e] = total;
        de[e] = total ? 1.f / (float)total : 0.f;
      }
    }
  } else if (bid < 512) {
    // ---- rfill: 1 row per wave, float4 (cols 4L..4L+3 per lane per round)
    int n = (bid - 256) * 8 + wv;
    const float* row = H + (size_t)n * EE;
    int count = 0;
    #pragma unroll
    for (int it = 0; it < 4; ++it) {
      float4 hv = *(const float4*)&row[it * 256 + lane * 4];
      float va[4] = {hv.x, hv.y, hv.z, hv.w};
      ull m[4];
      #pragma unroll
      for (int c2 = 0; c2 < 4; ++c2) m[c2] = __ballot(va[c2] != 0.f);
      int rl = 0;
      #pragma unroll
      for (int c2 = 0; c2 < 4; ++c2) rl += __popcll(m[c2] & below);
      int within = 0;
      #pragma unroll
      for (int c2 = 0; c2 < 4; ++c2) {
        if (va[c2] != 0.f) {
          int pos = count + rl + within;
          if (pos < 128) elist[n * 128 + pos] = (ushortt)(it * 256 + lane * 4 + c2);
          ++within;
        }
      }
      #pragma unroll
      for (int c2 = 0; c2 < 4; ++c2) count += __popcll(m[c2]);
    }
    if (lane == 0) {
      cnt[n] = count;
      dn[n] = count ? rsqrtf((float)count) : 0.f;
    }
  } else {
    // ---- npb: 8 rows x 128 h; W1 node-half transposed in LDS
    float* Wt = smem;
    float* xl = smem + 64 * 129;
    int r0 = (bid - 512) * 8;
    #pragma unroll
    for (int p = 0; p < 16; ++p) {
      int j = t + p * 512;
      int h = j >> 6, d = j & 63;
      Wt[d * 129 + h] = W1[h * 128 + d];
    }
    {
      int r = t >> 6, d = t & 63;   // 512 threads = 8 rows x 64
      xl[r * 64 + d] = x[(size_t)(r0 + r) * 64 + d];
    }
    __syncthreads();
    #pragma unroll
    for (int k = 0; k < 2; ++k) {
      int idx = t + k * 512;
      int row = idx >> 7, h = idx & 127;
      float acc = b1[h];
      #pragma unroll 8
      for (int d = 0; d < 64; ++d)
        acc += xl[row * 64 + d] * Wt[d * 129 + h];
      npb[(size_t)(r0 + row) * 128 + h] = acc;
    }
  }
}

// ---------------------------------------------------------------------------
// D2 k_edge (grid EE x 512 threads): ef gather + projection + batched col
// scores + w.  8-wave strided gathers (~13 iters); scores 128 entries/batch.
// Sigma bridge contiguous in svc[e*192+j] (block-local lines only).
// ---------------------------------------------------------------------------
__global__ __launch_bounds__(512)
void k_edge(const ushortt* __restrict__ clist,
            const int* __restrict__ ccnt, const float* __restrict__ de,
            const float* __restrict__ dn, const float* __restrict__ x,
            const float* __restrict__ W1, const float* __restrict__ npb,
            const float* __restrict__ W2, const float* __restrict__ b2,
            float* __restrict__ svc, float* __restrict__ w) {
  __shared__ __align__(16) float Wt[64 * 129];   // 33024 B
  __shared__ __align__(16) float psum[8][64];
  __shared__ __align__(16) float efl[64];
  __shared__ __align__(16) float epl[128];
  __shared__ __align__(16) float pp[4][128];
  __shared__ __align__(16) float w2l[128];
  __shared__ __align__(16) float sval[192];
  __shared__ __align__(16) ushortt cls[192];
  int t = threadIdx.x, wv = t >> 6, lane = t & 63;
  int e = blockIdx.x;
  int c = min(ccnt[e], 192);
  #pragma unroll
  for (int p = 0; p < 16; ++p) {
    int j = t + p * 512;
    int h = j >> 6, d = j & 63;
    Wt[d * 129 + h] = W1[h * 128 + 64 + d];
  }
  if (t < 128) w2l[t] = W2[t];
  if (t < 96) ((uint*)cls)[t] = ((const uint*)(clist + (size_t)e * 192))[t];
  __syncthreads();
  // pass 1: ef gather (8-wave strided, coalesced x rows)
  float acc = 0.f;
  for (int j = wv; j < c; j += 8) {
    int n = cls[j];
    acc += x[(size_t)n * 64 + lane];
  }
  psum[wv][lane] = acc;
  __syncthreads();
  if (wv == 0) {
    float s = 0.f;
    #pragma unroll
    for (int u = 0; u < 8; ++u) s += psum[u][lane];
    efl[lane] = s;
  }
  __syncthreads();
  // projection: 512 threads = 128 h x 4 d-quarters
  {
    int h = t & 127, q = t >> 7;
    float a = 0.f;
    #pragma unroll
    for (int d = q * 16; d < q * 16 + 16; ++d)
      a += efl[d] * Wt[d * 129 + h];
    pp[q][h] = a;
  }
  __syncthreads();
  if (t < 128) epl[t] = pp[0][t] + pp[1][t] + pp[2][t] + pp[3][t];
  __syncthreads();
  // batched scores: 128 entries x 4 subs (32 h each); sigma -> svc
  {
    int sub = t & 3, jloc = t >> 2;   // jloc 0..127
    float b2v = b2[0];
    int nb = (c + 127) >> 7;
    for (int b = 0; b < nb; ++b) {
      int j = b * 128 + jloc;
      if (j < c) {
        int n = cls[j];
        const float* npr = npb + (size_t)n * 128;
        float a = 0.f;
        #pragma unroll
        for (int q = 0; q < 8; ++q) {
          int o = q * 16 + sub * 4;
          float4 av = *(const float4*)&npr[o];
          float4 ev = *(const float4*)&epl[o];
          float4 w2 = *(const float4*)&w2l[o];
          a += fmaxf(av.x + ev.x, 0.f) * w2.x + fmaxf(av.y + ev.y, 0.f) * w2.y
             + fmaxf(av.z + ev.z, 0.f) * w2.z + fmaxf(av.w + ev.w, 0.f) * w2.w;
        }
        a += __shfl_xor(a, 1, 64);
        a += __shfl_xor(a, 2, 64);
        if (sub == 0) {
          float sg = 1.f / (1.f + __expf(-(a + b2v)));
          sval[j] = dn[n] * sg;
          svc[(size_t)e * 192 + j] = sg;
        }
      }
    }
  }
  __syncthreads();
  // pass 2: weighted gather
  float accw = 0.f;
  for (int j = wv; j < c; j += 8) {
    int n = cls[j];
    accw += sval[j] * x[(size_t)n * 64 + lane];
  }
  psum[wv][lane] = accw;
  __syncthreads();
  if (wv == 0) {
    float s = 0.f;
    #pragma unroll
    for (int u = 0; u < 8; ++u) s += psum[u][lane];
    w[(size_t)e * 64 + lane] = de[e] * s;
  }
}

// ---------------------------------------------------------------------------
// D3 k_node (grid NN/2 x 512 threads): 2 nodes/block, 4 waves per node.
// sigma via binary search in sorted clist[e]; z gather ~13 iters; fused
// final linear (2 nodes x 64 o x 4 d-quarters).
// ---------------------------------------------------------------------------
__global__ __launch_bounds__(512)
void k_node(const ushortt* __restrict__ elist, const int* __restrict__ cnt,
            const float* __restrict__ dn,
            const ushortt* __restrict__ clist, const int* __restrict__ ccnt,
            const float* __restrict__ svc, const float* __restrict__ w,
            const float* __restrict__ Wlg, const float* __restrict__ bl,
            float* __restrict__ out) {
  __shared__ __align__(16) float Wlds[64 * 65];  // 16640 B
  __shared__ __align__(16) float sval[2][128];
  __shared__ __align__(16) float psum[8][64];    // also reused as pp[4][128]
  __shared__ __align__(16) float zl[2][64];
  __shared__ __align__(16) ushortt els[2][128];
  int t = threadIdx.x, wv = t >> 6, lane = t & 63;
  int n0 = blockIdx.x * 2;
  #pragma unroll
  for (int p = 0; p < 8; ++p) {
    int j = t + p * 512;
    Wlds[(j >> 6) * 65 + (j & 63)] = Wlg[j];
  }
  if (t < 128) ((uint*)els)[t] = ((const uint*)(elist + (size_t)n0 * 128))[t];
  __syncthreads();
  // sigma search: thread t<256 covers node t>>7, entry t&127
  if (t < 256) {
    int nd = t >> 7, jj = t & 127;
    int n = n0 + nd;
    int c = min(cnt[n], 128);
    if (jj < c) {
      int e = els[nd][jj];
      const ushortt* cl = clist + (size_t)e * 192;
      int lo = 0, hi = min(ccnt[e], 192);
      while (lo < hi) {          // <=8 iters; entry guaranteed present
        int mid = (lo + hi) >> 1;
        if (cl[mid] < n) lo = mid + 1; else hi = mid;
      }
      sval[nd][jj] = svc[(size_t)e * 192 + lo];
    }
  }
  __syncthreads();
  // z gather: waves 0-3 -> node 0, 4-7 -> node 1; j strided by 4
  {
    int nd = wv >> 2;
    int n = n0 + nd;
    int c = min(cnt[n], 128);
    float acc = 0.f;
    for (int j = wv & 3; j < c; j += 4) {
      int e = els[nd][j];
      acc += sval[nd][j] * w[(size_t)e * 64 + lane];
    }
    psum[wv][lane] = acc;
    __syncthreads();
    if ((wv & 3) == 0)
      zl[nd][lane] = dn[n] * (psum[wv][lane] + psum[wv + 1][lane] +
                              psum[wv + 2][lane] + psum[wv + 3][lane]);
  }
  __syncthreads();
  // final linear: 512 threads = 4 d-quarters x 2 nodes x 64 o
  {
    float* pp = (float*)psum;    // [4][128]
    int o = t & 63, nd = (t >> 6) & 1, q = t >> 7;
    float po = 0.f;
    #pragma unroll
    for (int d = q * 16; d < q * 16 + 16; ++d)
      po += zl[nd][d] * Wlds[o * 65 + d];
    pp[q * 128 + nd * 64 + o] = po;
    __syncthreads();
    if (t < 128) {
      int ndo = t >> 6, oo = t & 63;
      out[(size_t)(n0 + ndo) * 64 + oo] =
          bl[oo] + pp[0 * 128 + t] + pp[1 * 128 + t] + pp[2 * 128 + t] + pp[3 * 128 + t];
    }
  }
}

extern "C" void kernel_launch(void* const* d_in, const int* in_sizes, int n_in,
                              void* d_out, int out_size, void* d_ws, size_t ws_size,
                              hipStream_t stream) {
  const float* x  = (const float*)d_in[0];
  const float* H  = (const float*)d_in[1];
  const float* W1 = (const float*)d_in[2];
  const float* b1 = (const float*)d_in[3];
  const float* W2 = (const float*)d_in[4];
  const float* b2 = (const float*)d_in[5];
  const float* Wl = (const float*)d_in[6];
  const float* bl = (const float*)d_in[7];
  float* out = (float*)d_out;

  char* wsb = (char*)d_ws;
  float* dn   = (float*)wsb;  wsb += NN * 4;
  float* de   = (float*)wsb;  wsb += EE * 4;
  int*   cnt  = (int*)wsb;    wsb += NN * 4;
  int*   ccnt = (int*)wsb;    wsb += EE * 4;
  float* npb  = (float*)wsb;  wsb += (size_t)NN * 128 * 4;
  float* w    = (float*)wsb;  wsb += (size_t)EE * 64 * 4;
  float* svc  = (float*)wsb;  wsb += (size_t)EE * 192 * 4;
  ushortt* elist = (ushortt*)wsb; wsb += (size_t)NN * 128 * 2;
  ushortt* clist = (ushortt*)wsb; wsb += (size_t)EE * 192 * 2;

  hipLaunchKernelGGL(k_scan, dim3(768), dim3(512), 0, stream,
                     H, x, W1, b1, elist, cnt, dn, clist, ccnt, de, npb);
  hipLaunchKernelGGL(k_edge, dim3(EE), dim3(512), 0, stream,
                     clist, ccnt, de, dn, x, W1, npb, W2, b2, svc, w);
  hipLaunchKernelGGL(k_node, dim3(NN / 2), dim3(512), 0, stream,
                     elist, cnt, dn, clist, ccnt, svc, w, Wl, bl, out);
}